// Round 21
// baseline (154.080 us; speedup 1.0000x reference)
//
#include <hip/hip_runtime.h>
#include <hip/hip_bf16.h>
#include <cstdint>
#include <cstddef>

typedef float  f32x4   __attribute__((ext_vector_type(4)));
typedef __bf16 bf16x8  __attribute__((ext_vector_type(8)));
typedef __bf16 bf16x4  __attribute__((ext_vector_type(4)));

#define NHEAD 12
#define DMODEL 768
#define HDIM 64
#define BATCH 2
#define NQ 1024
#define NS 4096
#define BH 24
#define KDIM 768
#define NSPLIT 4
#define LOG2E 1.4426950408889634f

__device__ __forceinline__ void gll16(const void* g, void* l) {
  __builtin_amdgcn_global_load_lds(
      (const __attribute__((address_space(1))) void*)g,
      (__attribute__((address_space(3))) void*)l, 16, 0, 0);
}

__device__ __forceinline__ void cvt8(const float* __restrict__ sp, __bf16* __restrict__ dp) {
  const float4 v0 = *(const float4*)sp;
  const float4 v1 = *(const float4*)(sp + 4);
  bf16x8 pk;
  pk[0] = (__bf16)v0.x; pk[1] = (__bf16)v0.y; pk[2] = (__bf16)v0.z; pk[3] = (__bf16)v0.w;
  pk[4] = (__bf16)v1.x; pk[5] = (__bf16)v1.y; pk[6] = (__bf16)v1.z; pk[7] = (__bf16)v1.w;
  *(bf16x8*)dp = pk;
}

// ---------------------------------------------------------------------------
// prep0: fused {per-batch mask scan | weight fp32->bf16 | query fp32->bf16}.
// grid.x = 2 (scan) + 1152 (convw) + 768 (convq).  (round-15 proven)
// ---------------------------------------------------------------------------
__global__ __launch_bounds__(256) void prep0(
    const float* __restrict__ mask, int* __restrict__ pos, int* __restrict__ nv,
    const float* __restrict__ Wq, const float* __restrict__ Wk,
    const float* __restrict__ Wv, const float* __restrict__ Wo,
    __bf16* __restrict__ wb4,
    const float* __restrict__ query, __bf16* __restrict__ qo)
{
  const int blk = blockIdx.x;
  const int t   = threadIdx.x;
  __shared__ int sc[256];

  if (blk < 2) {                       // ---- scan_mask, b = blk ----
    const int b = blk;
    const float* m = mask + (size_t)b * NS;
    int loc[16], s = 0;
    const int base = t * 16;
    #pragma unroll
    for (int i = 0; i < 16; ++i) { loc[i] = s; s += (m[base + i] > 0.5f) ? 1 : 0; }
    sc[t] = s;
    __syncthreads();
    for (int d = 1; d < 256; d <<= 1) {
      const int v = (t >= d) ? sc[t - d] : 0;
      __syncthreads();
      sc[t] += v;
      __syncthreads();
    }
    const int excl = sc[t] - s;
    int* pb = pos + (size_t)b * NS;
    #pragma unroll
    for (int i = 0; i < 16; ++i) pb[base + i] = excl + loc[i];
    if (t == 255) nv[b] = sc[255];
  } else if (blk < 2 + 1152) {         // ---- convw ----
    const int idx = blk - 2;
    const int mat = idx / 288, xb = idx % 288;
    const float* s;
    switch (mat) { case 0: s = Wq; break; case 1: s = Wk; break;
                   case 2: s = Wv; break; default: s = Wo; }
    const int i = (xb * 256 + t) * 8;
    cvt8(&s[i], &wb4[(size_t)mat * (DMODEL * KDIM) + i]);
  } else {                             // ---- convq ----
    const int xb = blk - (2 + 1152);
    const int i = (xb * 256 + t) * 8;
    cvt8(&query[i], &qo[i]);
  }
}

// ---------------------------------------------------------------------------
// Gather + convert valid K/V rows to compact bf16 buffers (round-13 proven).
// ---------------------------------------------------------------------------
__global__ __launch_bounds__(256) void gatherkv(
    const float* __restrict__ K, const float* __restrict__ V,
    const float* __restrict__ mask, const int* __restrict__ pos,
    __bf16* __restrict__ Xkc, __bf16* __restrict__ Xvc)
{
  const float* src = blockIdx.y ? V : K;
  __bf16*      dst = blockIdx.y ? Xvc : Xkc;
  const int half = threadIdx.x >> 7;
  const int tt   = threadIdx.x & 127;
  const int r    = blockIdx.x * 2 + half;
  if (tt >= 96) return;
  if (mask[r] <= 0.5f) return;
  const int b    = r >> 12;
  const int drow = (b << 12) + pos[r];
  cvt8(src + (size_t)r * DMODEL + tt * 8, &dst[(size_t)drow * DMODEL + tt * 8]);
}

// ---------------------------------------------------------------------------
// Merged Q/K/V projection (round-13 proven, unchanged).
// ---------------------------------------------------------------------------
__global__ __launch_bounds__(256) void qkvproj(
    const __bf16* __restrict__ Xqb, const __bf16* __restrict__ Xkb,
    const __bf16* __restrict__ Xvb, const __bf16* __restrict__ wb4,
    const int* __restrict__ nv,
    __bf16* __restrict__ Qb, __bf16* __restrict__ Kb, __bf16* __restrict__ VtG)
{
  const int y = blockIdx.y;
  int mode, m0;
  const __bf16* Xb;
  const __bf16* Wb;
  if (y < 16)      { mode = 0; m0 = y * 128;        Xb = Xqb; Wb = wb4; }
  else if (y < 80) { mode = 1; m0 = (y - 16) * 128; Xb = Xkb; Wb = wb4 + 589824; }
  else             { mode = 2; m0 = (y - 80) * 128; Xb = Xvb; Wb = wb4 + 2 * 589824; }

  if (mode != 0 && (m0 & (NS - 1)) >= nv[m0 >> 12]) return;

  const int n0   = blockIdx.x * 128;
  const int t    = threadIdx.x;
  const int lane = t & 63;
  const int wave = t >> 6;
  const int wr   = wave >> 1, wc = wave & 1;
  const int frow = lane & 15, hi = lane >> 4;

  __shared__ __align__(16) __bf16 As[128 * 64];
  __shared__ __align__(16) __bf16 Bs[128 * 64];

  f32x4 acc[4][4] = {};
  const int srow  = t >> 3;
  const int sslot = t & 7;

  for (int k0 = 0; k0 < KDIM; k0 += 64) {
    __syncthreads();
    #pragma unroll
    for (int i = 0; i < 4; ++i) {
      const int row = i * 32 + srow;
      const int cs  = (sslot ^ (row & 7)) * 8;
      gll16(&Wb[(size_t)(n0 + row) * KDIM + k0 + cs],
            (char*)Bs + i * 4096 + wave * 1024);
      gll16(&Xb[(size_t)(m0 + row) * KDIM + k0 + cs],
            (char*)As + i * 4096 + wave * 1024);
    }
    __syncthreads();

    #pragma unroll
    for (int ks = 0; ks < 2; ++ks) {
      bf16x8 af[4], bfr[4];
      #pragma unroll
      for (int mi = 0; mi < 4; ++mi) {
        const int row = wr * 64 + mi * 16 + frow;
        af[mi] = *(const bf16x8*)&As[row * 64 + ((ks * 4 + hi) ^ (frow & 7)) * 8];
      }
      #pragma unroll
      for (int ni = 0; ni < 4; ++ni) {
        const int row = wc * 64 + ni * 16 + frow;
        bfr[ni] = *(const bf16x8*)&Bs[row * 64 + ((ks * 4 + hi) ^ (frow & 7)) * 8];
      }
      #pragma unroll
      for (int mi = 0; mi < 4; ++mi)
        #pragma unroll
        for (int ni = 0; ni < 4; ++ni)
          acc[mi][ni] = __builtin_amdgcn_mfma_f32_16x16x32_bf16(
              af[mi], bfr[ni], acc[mi][ni], 0, 0, 0);
    }
  }

  if (mode == 0) {
    #pragma unroll
    for (int mi = 0; mi < 4; ++mi)
      #pragma unroll
      for (int ni = 0; ni < 4; ++ni)
        #pragma unroll
        for (int rr = 0; rr < 4; ++rr) {
          const int row = m0 + wr * 64 + mi * 16 + hi * 4 + rr;
          const int col = n0 + wc * 64 + ni * 16 + frow;
          Qb[(size_t)row * DMODEL + col] = (__bf16)acc[mi][ni][rr];
        }
  } else if (mode == 1) {
    #pragma unroll
    for (int mi = 0; mi < 4; ++mi)
      #pragma unroll
      for (int ni = 0; ni < 4; ++ni)
        #pragma unroll
        for (int rr = 0; rr < 4; ++rr) {
          const int row = m0 + wr * 64 + mi * 16 + hi * 4 + rr;
          const int col = n0 + wc * 64 + ni * 16 + frow;
          Kb[(size_t)row * DMODEL + col] = (__bf16)acc[mi][ni][rr];
        }
  } else {
    #pragma unroll
    for (int mi = 0; mi < 4; ++mi) {
      const int row0 = m0 + wr * 64 + mi * 16 + hi * 4;
      const int bb = row0 >> 12;
      const int kv = row0 & (NS - 1);
      #pragma unroll
      for (int ni = 0; ni < 4; ++ni) {
        bf16x4 pk;
        #pragma unroll
        for (int rr = 0; rr < 4; ++rr) pk[rr] = (__bf16)acc[mi][ni][rr];
        const int dg = n0 + wc * 64 + ni * 16 + frow;
        const int hh = dg >> 6, dd = dg & 63;
        *(bf16x4*)&VtG[(((size_t)bb * NHEAD + hh) * HDIM + dd) * NS + kv] = pk;
      }
    }
  }
}

// ---------------------------------------------------------------------------
// Out projection (round-8 proven, unchanged).
// ---------------------------------------------------------------------------
__global__ __launch_bounds__(256) void outproj(
    const __bf16* __restrict__ Xb, const __bf16* __restrict__ Wb,
    float* __restrict__ Yf, const float* __restrict__ bias)
{
  const int n0   = blockIdx.x * 128;
  const int m0   = blockIdx.y * 128;
  const int t    = threadIdx.x;
  const int lane = t & 63;
  const int wave = t >> 6;
  const int wr   = wave >> 1, wc = wave & 1;
  const int frow = lane & 15, hi = lane >> 4;

  __shared__ __align__(16) __bf16 As[128 * 64];
  __shared__ __align__(16) __bf16 Bs[128 * 64];

  f32x4 acc[4][4] = {};
  const int srow  = t >> 3;
  const int sslot = t & 7;

  for (int k0 = 0; k0 < KDIM; k0 += 64) {
    __syncthreads();
    #pragma unroll
    for (int i = 0; i < 4; ++i) {
      const int row = i * 32 + srow;
      const int cs  = (sslot ^ (row & 7)) * 8;
      gll16(&Wb[(size_t)(n0 + row) * KDIM + k0 + cs],
            (char*)Bs + i * 4096 + wave * 1024);
      gll16(&Xb[(size_t)(m0 + row) * KDIM + k0 + cs],
            (char*)As + i * 4096 + wave * 1024);
    }
    __syncthreads();

    #pragma unroll
    for (int ks = 0; ks < 2; ++ks) {
      bf16x8 af[4], bfr[4];
      #pragma unroll
      for (int mi = 0; mi < 4; ++mi) {
        const int row = wr * 64 + mi * 16 + frow;
        af[mi] = *(const bf16x8*)&As[row * 64 + ((ks * 4 + hi) ^ (frow & 7)) * 8];
      }
      #pragma unroll
      for (int ni = 0; ni < 4; ++ni) {
        const int row = wc * 64 + ni * 16 + frow;
        bfr[ni] = *(const bf16x8*)&Bs[row * 64 + ((ks * 4 + hi) ^ (frow & 7)) * 8];
      }
      #pragma unroll
      for (int mi = 0; mi < 4; ++mi)
        #pragma unroll
        for (int ni = 0; ni < 4; ++ni)
          acc[mi][ni] = __builtin_amdgcn_mfma_f32_16x16x32_bf16(
              af[mi], bfr[ni], acc[mi][ni], 0, 0, 0);
    }
  }

  #pragma unroll
  for (int mi = 0; mi < 4; ++mi)
    #pragma unroll
    for (int ni = 0; ni < 4; ++ni) {
      const int col = n0 + wc * 64 + ni * 16 + frow;
      const float bv = bias[col];
      #pragma unroll
      for (int rr = 0; rr < 4; ++rr) {
        const int row = m0 + wr * 64 + mi * 16 + hi * 4 + rr;
        Yf[(size_t)row * DMODEL + col] = acc[mi][ni][rr] + bv;
      }
    }
}

// ---------------------------------------------------------------------------
// Flash attention over COMPACT KV.  Round-19 proven compute body; staging
// switched to T14 async split: REGLOAD(it+1) issued BEFORE compute(it)
// (HBM latency hides under QK+softmax+PV), DS-write after the read barrier.
// LDS layout and size unchanged (50,176 B -> 3 blocks/CU).  NSPLIT=4.
// ---------------------------------------------------------------------------
__global__ __launch_bounds__(256) void attn_fwd(
    const __bf16* __restrict__ Qb, const __bf16* __restrict__ Kb,
    const __bf16* __restrict__ VtG, const int* __restrict__ nv,
    __bf16* __restrict__ Opart, float* __restrict__ ml)
{
  const int qt   = blockIdx.x;
  const int h    = blockIdx.y;
  const int b    = blockIdx.z / NSPLIT;
  const int sp   = blockIdx.z % NSPLIT;
  const int t    = threadIdx.x;
  const int lane = t & 63;
  const int wave = t >> 6;
  const int frow = lane & 15;
  const int hi   = lane >> 4;

  const int nvb = nv[b];
  const int C   = (nvb + 127) >> 7;
  const int cps = (C + NSPLIT - 1) / NSPLIT;
  const int c0  = sp * cps;
  const int c1  = (c0 + cps < C) ? (c0 + cps) : C;
  const int bh  = b * NHEAD + h;

  if (c0 >= c1) {
    if (frow == 0) {
      #pragma unroll
      for (int r = 0; r < 4; ++r) {
        const int q = qt * 64 + wave * 16 + hi * 4 + r;
        const size_t mo = (((size_t)sp * BH + bh) * NQ + q) * 2;
        ml[mo]     = -1e30f;
        ml[mo + 1] = 0.f;
      }
    }
    return;
  }

  __shared__ __align__(16) __bf16 Ks[128 * 64];
  __shared__ __align__(16) __bf16 Vts[64 * 128];
  __shared__ __align__(16) __bf16 Ps[4][16][136];

  const float C1 = 0.125f * LOG2E;

  const size_t kbase = (size_t)b * NS * DMODEL + h * HDIM;
  const size_t vbase = ((size_t)b * NHEAD + h) * HDIM * (size_t)NS;

  bf16x8 aq0, aq1;
  {
    const __bf16* qp = &Qb[((size_t)(b * NQ + qt * 64 + wave * 16 + frow)) * DMODEL + h * HDIM + hi * 8];
    aq0 = *(const bf16x8*)qp;
    aq1 = *(const bf16x8*)(qp + 32);
  }

  float m_r[4], l_r[4];
  f32x4 oacc[4] = {};
  #pragma unroll
  for (int r = 0; r < 4; ++r) { m_r[r] = -INFINITY; l_r[r] = 0.f; }

  const int krow_l = lane >> 3;
  const int kslot_ = lane & 7;
  const int vrow_l = lane >> 4;
  const int vslot_ = lane & 15;

  uint4 kr[4], vr[4];

#define REGLOAD(S0) do { \
    _Pragma("unroll") \
    for (int r4 = 0; r4 < 4; ++r4) { \
      const int strip = r4 * 4 + wave; \
      const int krow  = strip * 8 + krow_l; \
      kr[r4] = *(const uint4*)&Kb[kbase + (size_t)((S0) + krow) * DMODEL + ((kslot_ ^ (krow & 7)) << 3)]; \
      const int vrow  = strip * 4 + vrow_l; \
      vr[r4] = *(const uint4*)&VtG[vbase + (size_t)vrow * NS + (S0) + ((vslot_ ^ (vrow & 7)) << 3)]; \
    } } while (0)

#define DSWRITE() do { \
    _Pragma("unroll") \
    for (int r4 = 0; r4 < 4; ++r4) { \
      const int strip = r4 * 4 + wave; \
      *(uint4*)((char*)Ks + strip * 1024 + lane * 16) = kr[r4]; \
      *(uint4*)((char*)Vts + strip * 1024 + lane * 16) = vr[r4]; \
    } } while (0)

  // ---- prologue: stage first chunk ----
  REGLOAD(c0 * 128);
  DSWRITE();
  __syncthreads();

  #pragma unroll 1
  for (int it = c0; it < c1; ++it) {
    const int s0 = it * 128;
    const bool more = (it + 1 < c1);     // block-uniform

    if (more) REGLOAD(s0 + 128);         // in flight during compute

    // ---- scores: 16 q-rows x 128 kv per wave ----
    f32x4 sacc[8];
    #pragma unroll
    for (int j = 0; j < 8; ++j) {
      f32x4 z = {};
      const int row = j * 16 + frow;
      bf16x8 b0 = *(const bf16x8*)&Ks[row * 64 + ((hi    ) ^ (frow & 7)) * 8];
      z = __builtin_amdgcn_mfma_f32_16x16x32_bf16(aq0, b0, z, 0, 0, 0);
      bf16x8 b1 = *(const bf16x8*)&Ks[row * 64 + ((4 + hi) ^ (frow & 7)) * 8];
      sacc[j] = __builtin_amdgcn_mfma_f32_16x16x32_bf16(aq1, b1, z, 0, 0, 0);
    }

    // ---- online softmax (log2 domain); bias = compare vs nv ----
    float rmax[4] = {-INFINITY, -INFINITY, -INFINITY, -INFINITY};
    #pragma unroll
    for (int j = 0; j < 8; ++j) {
      const float addm = (s0 + j * 16 + frow < nvb) ? 0.f : -1e30f;
      #pragma unroll
      for (int r = 0; r < 4; ++r) {
        const float s = sacc[j][r] * C1 + addm;
        sacc[j][r] = s;
        rmax[r] = fmaxf(rmax[r], s);
      }
    }
    #pragma unroll
    for (int r = 0; r < 4; ++r) {
      rmax[r] = fmaxf(rmax[r], __shfl_xor(rmax[r], 1));
      rmax[r] = fmaxf(rmax[r], __shfl_xor(rmax[r], 2));
      rmax[r] = fmaxf(rmax[r], __shfl_xor(rmax[r], 4));
      rmax[r] = fmaxf(rmax[r], __shfl_xor(rmax[r], 8));
    }
    float sf[4];
    #pragma unroll
    for (int r = 0; r < 4; ++r) {
      const float mnew = fmaxf(m_r[r], rmax[r]);
      sf[r] = exp2f(m_r[r] - mnew);
      m_r[r] = mnew;
    }
    float rs[4] = {0.f, 0.f, 0.f, 0.f};
    #pragma unroll
    for (int j = 0; j < 8; ++j)
      #pragma unroll
      for (int r = 0; r < 4; ++r) {
        const float e = exp2f(sacc[j][r] - m_r[r]);
        sacc[j][r] = e;
        rs[r] += e;
      }
    #pragma unroll
    for (int r = 0; r < 4; ++r) {
      rs[r] += __shfl_xor(rs[r], 1);
      rs[r] += __shfl_xor(rs[r], 2);
      rs[r] += __shfl_xor(rs[r], 4);
      rs[r] += __shfl_xor(rs[r], 8);
      l_r[r] = l_r[r] * sf[r] + rs[r];
    }
    #pragma unroll
    for (int j = 0; j < 4; ++j)
      #pragma unroll
      for (int r = 0; r < 4; ++r)
        oacc[j][r] *= sf[r];

    // ---- P -> wave-private LDS (same-wave RAW, no barrier) ----
    #pragma unroll
    for (int j = 0; j < 8; ++j)
      #pragma unroll
      for (int r = 0; r < 4; ++r)
        Ps[wave][hi * 4 + r][j * 16 + frow] = (__bf16)sacc[j][r];

    // ---- O += P V  (K=128 over 4 groups) ----
    bf16x8 pa[4];
    #pragma unroll
    for (int g = 0; g < 4; ++g)
      pa[g] = *(const bf16x8*)&Ps[wave][frow][g * 32 + hi * 8];
    #pragma unroll
    for (int jd = 0; jd < 4; ++jd) {
      const int row = jd * 16 + frow;
      #pragma unroll
      for (int g = 0; g < 4; ++g) {
        bf16x8 bv = *(const bf16x8*)&Vts[row * 128 + (((g * 4 + hi) ^ (frow & 7)) << 3)];
        oacc[jd] = __builtin_amdgcn_mfma_f32_16x16x32_bf16(pa[g], bv, oacc[jd], 0, 0, 0);
      }
    }

    __syncthreads();                     // all waves done reading Ks/Vts
    if (more) {
      DSWRITE();                         // waits vmcnt for kr/vr, then ds_write
      __syncthreads();                   // next chunk visible to all waves
    }
  }
#undef REGLOAD
#undef DSWRITE

  // ---- epilogue: unnormalized bf16 partials + (m,l) ----
  #pragma unroll
  for (int j = 0; j < 4; ++j)
    #pragma unroll
    for (int r = 0; r < 4; ++r) {
      const int q = qt * 64 + wave * 16 + hi * 4 + r;
      Opart[(((size_t)sp * BH + bh) * NQ + q) * HDIM + j * 16 + frow] =
          (__bf16)oacc[j][r];
    }
  if (frow == 0) {
    #pragma unroll
    for (int r = 0; r < 4; ++r) {
      const int q = qt * 64 + wave * 16 + hi * 4 + r;
      const size_t mo = (((size_t)sp * BH + bh) * NQ + q) * 2;
      ml[mo]     = m_r[r];
      ml[mo + 1] = l_r[r];
    }
  }
}

// ---------------------------------------------------------------------------
// Combine split partials (bf16 Opart) -> AObf.  exp2 domain.
// ---------------------------------------------------------------------------
__global__ __launch_bounds__(256) void attn_combine(
    const __bf16* __restrict__ Opart, const float* __restrict__ ml,
    __bf16* __restrict__ AObf)
{
  const int row = blockIdx.x * 4 + (threadIdx.x >> 6);
  const int d   = threadIdx.x & 63;
  const int bh  = row >> 10;
  const int q   = row & (NQ - 1);

  float M = -INFINITY;
  for (int s = 0; s < NSPLIT; ++s)
    M = fmaxf(M, ml[(((size_t)s * BH + bh) * NQ + q) * 2]);

  float L = 0.f, acc = 0.f;
  for (int s = 0; s < NSPLIT; ++s) {
    const size_t mo = (((size_t)s * BH + bh) * NQ + q) * 2;
    const float w = exp2f(ml[mo] - M);
    L   += w * ml[mo + 1];
    acc += w * (float)Opart[(((size_t)s * BH + bh) * NQ + q) * HDIM + d];
  }
  const int bb = bh / NHEAD, hh = bh % NHEAD;
  AObf[((size_t)(bb * NQ + q)) * DMODEL + hh * HDIM + d] = (__bf16)(acc / L);
}

// ---------------------------------------------------------------------------
extern "C" void kernel_launch(void* const* d_in, const int* in_sizes, int n_in,
                              void* d_out, int out_size, void* d_ws, size_t ws_size,
                              hipStream_t stream)
{
  const float* query = (const float*)d_in[0];
  const float* key   = (const float*)d_in[1];
  const float* value = (const float*)d_in[2];
  const float* mask  = (const float*)d_in[3];
  const float* Wq    = (const float*)d_in[4];
  const float* Wk    = (const float*)d_in[5];
  const float* Wv    = (const float*)d_in[6];
  const float* Wo    = (const float*)d_in[7];
  const float* bo    = (const float*)d_in[8];
  float* out = (float*)d_out;

  char* ws = (char*)d_ws;
  // workspace layout (bytes), total 61,374,720:
  //   wb4   bf16 4*768*768   @ 0           (4,718,592)
  //   pos   int  8192        @ 4,718,592   (32,768); nv int[2] @ +32,768
  //   Xqb   bf16 2048*768    @ 4,751,616   (3,145,728)   ml aliases (786,432)
  //   Xkc   bf16 8192*768    @ 7,897,344   (12,582,912)  Opart(bf16) aliases
  //   Xvc   bf16 8192*768    @ 20,480,256  (12,582,912)
  //   Qb    bf16 2048*768    @ 33,063,168  (3,145,728)   AObf aliases
  //   Kb    bf16 8192*768    @ 36,208,896  (12,582,912)
  //   VtG   bf16 24*64*4096  @ 48,791,808  (12,582,912)
  const size_t OFF_POS = 4718592,  OFF_XQ = 4751616,  OFF_XK = 7897344;
  const size_t OFF_XV  = 20480256, OFF_QB = 33063168, OFF_KB = 36208896;
  const size_t OFF_VT  = 48791808;
  __bf16* wb4  = (__bf16*)(ws);
  int*    pos  = (int*)(ws + OFF_POS);
  int*    nv   = (int*)(ws + OFF_POS + 32768);
  __bf16* Xqb  = (__bf16*)(ws + OFF_XQ);
  __bf16* Xkc  = (__bf16*)(ws + OFF_XK);
  __bf16* Xvc  = (__bf16*)(ws + OFF_XV);
  __bf16* Qb   = (__bf16*)(ws + OFF_QB);
  __bf16* AObf = Qb;                        // Qb dead after attn_fwd
  __bf16* Kb   = (__bf16*)(ws + OFF_KB);
  __bf16* VtG  = (__bf16*)(ws + OFF_VT);
  __bf16* Opb  = (__bf16*)(ws + OFF_XK);    // Xkc/Xvc dead after qkvproj
  float*  mlp  = (float*)(ws + OFF_XQ);     // Xqb dead after qkvproj

  const dim3 blk(256);
  prep0<<<dim3(2 + 1152 + 768), blk, 0, stream>>>(
      mask, pos, nv, Wq, Wk, Wv, Wo, wb4, query, Xqb);
  gatherkv<<<dim3(4096, 2), blk, 0, stream>>>(key, value, mask, pos, Xkc, Xvc);
  qkvproj<<<dim3(6, 144), blk, 0, stream>>>(Xqb, Xkc, Xvc, wb4, nv, Qb, Kb, VtG);

  attn_fwd<<<dim3(NQ / 64, NHEAD, BATCH * NSPLIT), blk, 0, stream>>>(
      Qb, Kb, VtG, nv, Opb, mlp);
  attn_combine<<<dim3((BH * NQ) / 4), blk, 0, stream>>>(Opb, mlp, AObf);

  outproj<<<dim3(6, 16), blk, 0, stream>>>(AObf, wb4 + 3 * 589824, out, bo);
}

// Round 22
// 122.622 us; speedup vs baseline: 1.2565x; 1.2565x over previous
//
#include <hip/hip_runtime.h>
#include <hip/hip_bf16.h>
#include <cstdint>
#include <cstddef>

typedef float  f32x4   __attribute__((ext_vector_type(4)));
typedef __bf16 bf16x8  __attribute__((ext_vector_type(8)));
typedef __bf16 bf16x4  __attribute__((ext_vector_type(4)));

#define NHEAD 12
#define DMODEL 768
#define HDIM 64
#define BATCH 2
#define NQ 1024
#define NS 4096
#define BH 24
#define KDIM 768
#define NSPLIT 4
#define LOG2E 1.4426950408889634f

__device__ __forceinline__ void gll16(const void* g, void* l) {
  __builtin_amdgcn_global_load_lds(
      (const __attribute__((address_space(1))) void*)g,
      (__attribute__((address_space(3))) void*)l, 16, 0, 0);
}

__device__ __forceinline__ void cvt8(const float* __restrict__ sp, __bf16* __restrict__ dp) {
  const float4 v0 = *(const float4*)sp;
  const float4 v1 = *(const float4*)(sp + 4);
  bf16x8 pk;
  pk[0] = (__bf16)v0.x; pk[1] = (__bf16)v0.y; pk[2] = (__bf16)v0.z; pk[3] = (__bf16)v0.w;
  pk[4] = (__bf16)v1.x; pk[5] = (__bf16)v1.y; pk[6] = (__bf16)v1.z; pk[7] = (__bf16)v1.w;
  *(bf16x8*)dp = pk;
}

// ---------------------------------------------------------------------------
// prep0: fused {per-batch mask scan | weight fp32->bf16 | query fp32->bf16}.
// grid.x = 2 (scan) + 1152 (convw) + 768 (convq).  (round-15 proven)
// ---------------------------------------------------------------------------
__global__ __launch_bounds__(256) void prep0(
    const float* __restrict__ mask, int* __restrict__ pos, int* __restrict__ nv,
    const float* __restrict__ Wq, const float* __restrict__ Wk,
    const float* __restrict__ Wv, const float* __restrict__ Wo,
    __bf16* __restrict__ wb4,
    const float* __restrict__ query, __bf16* __restrict__ qo)
{
  const int blk = blockIdx.x;
  const int t   = threadIdx.x;
  __shared__ int sc[256];

  if (blk < 2) {                       // ---- scan_mask, b = blk ----
    const int b = blk;
    const float* m = mask + (size_t)b * NS;
    int loc[16], s = 0;
    const int base = t * 16;
    #pragma unroll
    for (int i = 0; i < 16; ++i) { loc[i] = s; s += (m[base + i] > 0.5f) ? 1 : 0; }
    sc[t] = s;
    __syncthreads();
    for (int d = 1; d < 256; d <<= 1) {
      const int v = (t >= d) ? sc[t - d] : 0;
      __syncthreads();
      sc[t] += v;
      __syncthreads();
    }
    const int excl = sc[t] - s;
    int* pb = pos + (size_t)b * NS;
    #pragma unroll
    for (int i = 0; i < 16; ++i) pb[base + i] = excl + loc[i];
    if (t == 255) nv[b] = sc[255];
  } else if (blk < 2 + 1152) {         // ---- convw ----
    const int idx = blk - 2;
    const int mat = idx / 288, xb = idx % 288;
    const float* s;
    switch (mat) { case 0: s = Wq; break; case 1: s = Wk; break;
                   case 2: s = Wv; break; default: s = Wo; }
    const int i = (xb * 256 + t) * 8;
    cvt8(&s[i], &wb4[(size_t)mat * (DMODEL * KDIM) + i]);
  } else {                             // ---- convq ----
    const int xb = blk - (2 + 1152);
    const int i = (xb * 256 + t) * 8;
    cvt8(&query[i], &qo[i]);
  }
}

// ---------------------------------------------------------------------------
// Gather + convert valid K/V rows to compact bf16 buffers (round-13 proven).
// ---------------------------------------------------------------------------
__global__ __launch_bounds__(256) void gatherkv(
    const float* __restrict__ K, const float* __restrict__ V,
    const float* __restrict__ mask, const int* __restrict__ pos,
    __bf16* __restrict__ Xkc, __bf16* __restrict__ Xvc)
{
  const float* src = blockIdx.y ? V : K;
  __bf16*      dst = blockIdx.y ? Xvc : Xkc;
  const int half = threadIdx.x >> 7;
  const int tt   = threadIdx.x & 127;
  const int r    = blockIdx.x * 2 + half;
  if (tt >= 96) return;
  if (mask[r] <= 0.5f) return;
  const int b    = r >> 12;
  const int drow = (b << 12) + pos[r];
  cvt8(src + (size_t)r * DMODEL + tt * 8, &dst[(size_t)drow * DMODEL + tt * 8]);
}

// ---------------------------------------------------------------------------
// Merged Q/K/V projection (round-13 proven, unchanged).
// ---------------------------------------------------------------------------
__global__ __launch_bounds__(256) void qkvproj(
    const __bf16* __restrict__ Xqb, const __bf16* __restrict__ Xkb,
    const __bf16* __restrict__ Xvb, const __bf16* __restrict__ wb4,
    const int* __restrict__ nv,
    __bf16* __restrict__ Qb, __bf16* __restrict__ Kb, __bf16* __restrict__ VtG)
{
  const int y = blockIdx.y;
  int mode, m0;
  const __bf16* Xb;
  const __bf16* Wb;
  if (y < 16)      { mode = 0; m0 = y * 128;        Xb = Xqb; Wb = wb4; }
  else if (y < 80) { mode = 1; m0 = (y - 16) * 128; Xb = Xkb; Wb = wb4 + 589824; }
  else             { mode = 2; m0 = (y - 80) * 128; Xb = Xvb; Wb = wb4 + 2 * 589824; }

  if (mode != 0 && (m0 & (NS - 1)) >= nv[m0 >> 12]) return;

  const int n0   = blockIdx.x * 128;
  const int t    = threadIdx.x;
  const int lane = t & 63;
  const int wave = t >> 6;
  const int wr   = wave >> 1, wc = wave & 1;
  const int frow = lane & 15, hi = lane >> 4;

  __shared__ __align__(16) __bf16 As[128 * 64];
  __shared__ __align__(16) __bf16 Bs[128 * 64];

  f32x4 acc[4][4] = {};
  const int srow  = t >> 3;
  const int sslot = t & 7;

  for (int k0 = 0; k0 < KDIM; k0 += 64) {
    __syncthreads();
    #pragma unroll
    for (int i = 0; i < 4; ++i) {
      const int row = i * 32 + srow;
      const int cs  = (sslot ^ (row & 7)) * 8;
      gll16(&Wb[(size_t)(n0 + row) * KDIM + k0 + cs],
            (char*)Bs + i * 4096 + wave * 1024);
      gll16(&Xb[(size_t)(m0 + row) * KDIM + k0 + cs],
            (char*)As + i * 4096 + wave * 1024);
    }
    __syncthreads();

    #pragma unroll
    for (int ks = 0; ks < 2; ++ks) {
      bf16x8 af[4], bfr[4];
      #pragma unroll
      for (int mi = 0; mi < 4; ++mi) {
        const int row = wr * 64 + mi * 16 + frow;
        af[mi] = *(const bf16x8*)&As[row * 64 + ((ks * 4 + hi) ^ (frow & 7)) * 8];
      }
      #pragma unroll
      for (int ni = 0; ni < 4; ++ni) {
        const int row = wc * 64 + ni * 16 + frow;
        bfr[ni] = *(const bf16x8*)&Bs[row * 64 + ((ks * 4 + hi) ^ (frow & 7)) * 8];
      }
      #pragma unroll
      for (int mi = 0; mi < 4; ++mi)
        #pragma unroll
        for (int ni = 0; ni < 4; ++ni)
          acc[mi][ni] = __builtin_amdgcn_mfma_f32_16x16x32_bf16(
              af[mi], bfr[ni], acc[mi][ni], 0, 0, 0);
    }
  }

  if (mode == 0) {
    #pragma unroll
    for (int mi = 0; mi < 4; ++mi)
      #pragma unroll
      for (int ni = 0; ni < 4; ++ni)
        #pragma unroll
        for (int rr = 0; rr < 4; ++rr) {
          const int row = m0 + wr * 64 + mi * 16 + hi * 4 + rr;
          const int col = n0 + wc * 64 + ni * 16 + frow;
          Qb[(size_t)row * DMODEL + col] = (__bf16)acc[mi][ni][rr];
        }
  } else if (mode == 1) {
    #pragma unroll
    for (int mi = 0; mi < 4; ++mi)
      #pragma unroll
      for (int ni = 0; ni < 4; ++ni)
        #pragma unroll
        for (int rr = 0; rr < 4; ++rr) {
          const int row = m0 + wr * 64 + mi * 16 + hi * 4 + rr;
          const int col = n0 + wc * 64 + ni * 16 + frow;
          Kb[(size_t)row * DMODEL + col] = (__bf16)acc[mi][ni][rr];
        }
  } else {
    #pragma unroll
    for (int mi = 0; mi < 4; ++mi) {
      const int row0 = m0 + wr * 64 + mi * 16 + hi * 4;
      const int bb = row0 >> 12;
      const int kv = row0 & (NS - 1);
      #pragma unroll
      for (int ni = 0; ni < 4; ++ni) {
        bf16x4 pk;
        #pragma unroll
        for (int rr = 0; rr < 4; ++rr) pk[rr] = (__bf16)acc[mi][ni][rr];
        const int dg = n0 + wc * 64 + ni * 16 + frow;
        const int hh = dg >> 6, dd = dg & 63;
        *(bf16x4*)&VtG[(((size_t)bb * NHEAD + hh) * HDIM + dd) * NS + kv] = pk;
      }
    }
  }
}

// ---------------------------------------------------------------------------
// Out projection (round-8 proven, unchanged).
// ---------------------------------------------------------------------------
__global__ __launch_bounds__(256) void outproj(
    const __bf16* __restrict__ Xb, const __bf16* __restrict__ Wb,
    float* __restrict__ Yf, const float* __restrict__ bias)
{
  const int n0   = blockIdx.x * 128;
  const int m0   = blockIdx.y * 128;
  const int t    = threadIdx.x;
  const int lane = t & 63;
  const int wave = t >> 6;
  const int wr   = wave >> 1, wc = wave & 1;
  const int frow = lane & 15, hi = lane >> 4;

  __shared__ __align__(16) __bf16 As[128 * 64];
  __shared__ __align__(16) __bf16 Bs[128 * 64];

  f32x4 acc[4][4] = {};
  const int srow  = t >> 3;
  const int sslot = t & 7;

  for (int k0 = 0; k0 < KDIM; k0 += 64) {
    __syncthreads();
    #pragma unroll
    for (int i = 0; i < 4; ++i) {
      const int row = i * 32 + srow;
      const int cs  = (sslot ^ (row & 7)) * 8;
      gll16(&Wb[(size_t)(n0 + row) * KDIM + k0 + cs],
            (char*)Bs + i * 4096 + wave * 1024);
      gll16(&Xb[(size_t)(m0 + row) * KDIM + k0 + cs],
            (char*)As + i * 4096 + wave * 1024);
    }
    __syncthreads();

    #pragma unroll
    for (int ks = 0; ks < 2; ++ks) {
      bf16x8 af[4], bfr[4];
      #pragma unroll
      for (int mi = 0; mi < 4; ++mi) {
        const int row = wr * 64 + mi * 16 + frow;
        af[mi] = *(const bf16x8*)&As[row * 64 + ((ks * 4 + hi) ^ (frow & 7)) * 8];
      }
      #pragma unroll
      for (int ni = 0; ni < 4; ++ni) {
        const int row = wc * 64 + ni * 16 + frow;
        bfr[ni] = *(const bf16x8*)&Bs[row * 64 + ((ks * 4 + hi) ^ (frow & 7)) * 8];
      }
      #pragma unroll
      for (int mi = 0; mi < 4; ++mi)
        #pragma unroll
        for (int ni = 0; ni < 4; ++ni)
          acc[mi][ni] = __builtin_amdgcn_mfma_f32_16x16x32_bf16(
              af[mi], bfr[ni], acc[mi][ni], 0, 0, 0);
    }
  }

  #pragma unroll
  for (int mi = 0; mi < 4; ++mi)
    #pragma unroll
    for (int ni = 0; ni < 4; ++ni) {
      const int col = n0 + wc * 64 + ni * 16 + frow;
      const float bv = bias[col];
      #pragma unroll
      for (int rr = 0; rr < 4; ++rr) {
        const int row = m0 + wr * 64 + mi * 16 + hi * 4 + rr;
        Yf[(size_t)row * DMODEL + col] = acc[mi][ni][rr] + bv;
      }
    }
}

// ---------------------------------------------------------------------------
// Flash attention over COMPACT KV — round-19 measured-best body EXACTLY
// (gll16 staging, always-compare bias: 51.7 µs, VGPR 80, occ ~25%).
// NSPLIT=4 -> 1536 blocks.
// ---------------------------------------------------------------------------
__global__ __launch_bounds__(256) void attn_fwd(
    const __bf16* __restrict__ Qb, const __bf16* __restrict__ Kb,
    const __bf16* __restrict__ VtG, const int* __restrict__ nv,
    __bf16* __restrict__ Opart, float* __restrict__ ml)
{
  const int qt   = blockIdx.x;
  const int h    = blockIdx.y;
  const int b    = blockIdx.z / NSPLIT;
  const int sp   = blockIdx.z % NSPLIT;
  const int t    = threadIdx.x;
  const int lane = t & 63;
  const int wave = t >> 6;
  const int frow = lane & 15;
  const int hi   = lane >> 4;

  const int nvb = nv[b];
  const int C   = (nvb + 127) >> 7;
  const int cps = (C + NSPLIT - 1) / NSPLIT;
  const int c0  = sp * cps;
  const int c1  = (c0 + cps < C) ? (c0 + cps) : C;
  const int bh  = b * NHEAD + h;

  if (c0 >= c1) {
    if (frow == 0) {
      #pragma unroll
      for (int r = 0; r < 4; ++r) {
        const int q = qt * 64 + wave * 16 + hi * 4 + r;
        const size_t mo = (((size_t)sp * BH + bh) * NQ + q) * 2;
        ml[mo]     = -1e30f;
        ml[mo + 1] = 0.f;
      }
    }
    return;
  }

  __shared__ __align__(16) __bf16 Ks[128 * 64];
  __shared__ __align__(16) __bf16 Vts[64 * 128];
  __shared__ __align__(16) __bf16 Ps[4][16][136];

  const float C1 = 0.125f * LOG2E;

  const size_t kbase = (size_t)b * NS * DMODEL + h * HDIM;
  const size_t vbase = ((size_t)b * NHEAD + h) * HDIM * (size_t)NS;

  bf16x8 aq0, aq1;
  {
    const __bf16* qp = &Qb[((size_t)(b * NQ + qt * 64 + wave * 16 + frow)) * DMODEL + h * HDIM + hi * 8];
    aq0 = *(const bf16x8*)qp;
    aq1 = *(const bf16x8*)(qp + 32);
  }

  float m_r[4], l_r[4];
  f32x4 oacc[4] = {};
  #pragma unroll
  for (int r = 0; r < 4; ++r) { m_r[r] = -INFINITY; l_r[r] = 0.f; }

  const int krow_l = lane >> 3;
  const int kslot_ = lane & 7;
  const int vrow_l = lane >> 4;
  const int vslot_ = lane & 15;

  #pragma unroll 1
  for (int it = c0; it < c1; ++it) {
    const int s0 = it * 128;
    #pragma unroll
    for (int r4 = 0; r4 < 4; ++r4) {
      const int strip = r4 * 4 + wave;
      const int krow  = strip * 8 + krow_l;
      gll16(&Kb[kbase + (size_t)(s0 + krow) * DMODEL + ((kslot_ ^ (krow & 7)) << 3)],
            (char*)Ks + strip * 1024);
      const int vrow  = strip * 4 + vrow_l;
      gll16(&VtG[vbase + (size_t)vrow * NS + s0 + ((vslot_ ^ (vrow & 7)) << 3)],
            (char*)Vts + strip * 1024);
    }
    __syncthreads();

    // ---- scores: 16 q-rows x 128 kv per wave ----
    f32x4 sacc[8];
    #pragma unroll
    for (int j = 0; j < 8; ++j) {
      f32x4 z = {};
      const int row = j * 16 + frow;
      bf16x8 b0 = *(const bf16x8*)&Ks[row * 64 + ((hi    ) ^ (frow & 7)) * 8];
      z = __builtin_amdgcn_mfma_f32_16x16x32_bf16(aq0, b0, z, 0, 0, 0);
      bf16x8 b1 = *(const bf16x8*)&Ks[row * 64 + ((4 + hi) ^ (frow & 7)) * 8];
      sacc[j] = __builtin_amdgcn_mfma_f32_16x16x32_bf16(aq1, b1, z, 0, 0, 0);
    }

    // ---- online softmax (log2 domain); bias = compare vs nv ----
    float rmax[4] = {-INFINITY, -INFINITY, -INFINITY, -INFINITY};
    #pragma unroll
    for (int j = 0; j < 8; ++j) {
      const float addm = (s0 + j * 16 + frow < nvb) ? 0.f : -1e30f;
      #pragma unroll
      for (int r = 0; r < 4; ++r) {
        const float s = sacc[j][r] * C1 + addm;
        sacc[j][r] = s;
        rmax[r] = fmaxf(rmax[r], s);
      }
    }
    #pragma unroll
    for (int r = 0; r < 4; ++r) {
      rmax[r] = fmaxf(rmax[r], __shfl_xor(rmax[r], 1));
      rmax[r] = fmaxf(rmax[r], __shfl_xor(rmax[r], 2));
      rmax[r] = fmaxf(rmax[r], __shfl_xor(rmax[r], 4));
      rmax[r] = fmaxf(rmax[r], __shfl_xor(rmax[r], 8));
    }
    float sf[4];
    #pragma unroll
    for (int r = 0; r < 4; ++r) {
      const float mnew = fmaxf(m_r[r], rmax[r]);
      sf[r] = exp2f(m_r[r] - mnew);
      m_r[r] = mnew;
    }
    float rs[4] = {0.f, 0.f, 0.f, 0.f};
    #pragma unroll
    for (int j = 0; j < 8; ++j)
      #pragma unroll
      for (int r = 0; r < 4; ++r) {
        const float e = exp2f(sacc[j][r] - m_r[r]);
        sacc[j][r] = e;
        rs[r] += e;
      }
    #pragma unroll
    for (int r = 0; r < 4; ++r) {
      rs[r] += __shfl_xor(rs[r], 1);
      rs[r] += __shfl_xor(rs[r], 2);
      rs[r] += __shfl_xor(rs[r], 4);
      rs[r] += __shfl_xor(rs[r], 8);
      l_r[r] = l_r[r] * sf[r] + rs[r];
    }
    #pragma unroll
    for (int j = 0; j < 4; ++j)
      #pragma unroll
      for (int r = 0; r < 4; ++r)
        oacc[j][r] *= sf[r];

    // ---- P -> wave-private LDS (same-wave RAW, no barrier) ----
    #pragma unroll
    for (int j = 0; j < 8; ++j)
      #pragma unroll
      for (int r = 0; r < 4; ++r)
        Ps[wave][hi * 4 + r][j * 16 + frow] = (__bf16)sacc[j][r];

    // ---- O += P V  (K=128 over 4 groups) ----
    bf16x8 pa[4];
    #pragma unroll
    for (int g = 0; g < 4; ++g)
      pa[g] = *(const bf16x8*)&Ps[wave][frow][g * 32 + hi * 8];
    #pragma unroll
    for (int jd = 0; jd < 4; ++jd) {
      const int row = jd * 16 + frow;
      #pragma unroll
      for (int g = 0; g < 4; ++g) {
        bf16x8 bv = *(const bf16x8*)&Vts[row * 128 + (((g * 4 + hi) ^ (frow & 7)) << 3)];
        oacc[jd] = __builtin_amdgcn_mfma_f32_16x16x32_bf16(pa[g], bv, oacc[jd], 0, 0, 0);
      }
    }
    __syncthreads();
  }

  // ---- epilogue: unnormalized bf16 partials + (m,l) ----
  #pragma unroll
  for (int j = 0; j < 4; ++j)
    #pragma unroll
    for (int r = 0; r < 4; ++r) {
      const int q = qt * 64 + wave * 16 + hi * 4 + r;
      Opart[(((size_t)sp * BH + bh) * NQ + q) * HDIM + j * 16 + frow] =
          (__bf16)oacc[j][r];
    }
  if (frow == 0) {
    #pragma unroll
    for (int r = 0; r < 4; ++r) {
      const int q = qt * 64 + wave * 16 + hi * 4 + r;
      const size_t mo = (((size_t)sp * BH + bh) * NQ + q) * 2;
      ml[mo]     = m_r[r];
      ml[mo + 1] = l_r[r];
    }
  }
}

// ---------------------------------------------------------------------------
// Combine split partials (bf16 Opart) -> AObf.  exp2 domain.
// ---------------------------------------------------------------------------
__global__ __launch_bounds__(256) void attn_combine(
    const __bf16* __restrict__ Opart, const float* __restrict__ ml,
    __bf16* __restrict__ AObf)
{
  const int row = blockIdx.x * 4 + (threadIdx.x >> 6);
  const int d   = threadIdx.x & 63;
  const int bh  = row >> 10;
  const int q   = row & (NQ - 1);

  float M = -INFINITY;
  for (int s = 0; s < NSPLIT; ++s)
    M = fmaxf(M, ml[(((size_t)s * BH + bh) * NQ + q) * 2]);

  float L = 0.f, acc = 0.f;
  for (int s = 0; s < NSPLIT; ++s) {
    const size_t mo = (((size_t)s * BH + bh) * NQ + q) * 2;
    const float w = exp2f(ml[mo] - M);
    L   += w * ml[mo + 1];
    acc += w * (float)Opart[(((size_t)s * BH + bh) * NQ + q) * HDIM + d];
  }
  const int bb = bh / NHEAD, hh = bh % NHEAD;
  AObf[((size_t)(bb * NQ + q)) * DMODEL + hh * HDIM + d] = (__bf16)(acc / L);
}

// ---------------------------------------------------------------------------
extern "C" void kernel_launch(void* const* d_in, const int* in_sizes, int n_in,
                              void* d_out, int out_size, void* d_ws, size_t ws_size,
                              hipStream_t stream)
{
  const float* query = (const float*)d_in[0];
  const float* key   = (const float*)d_in[1];
  const float* value = (const float*)d_in[2];
  const float* mask  = (const float*)d_in[3];
  const float* Wq    = (const float*)d_in[4];
  const float* Wk    = (const float*)d_in[5];
  const float* Wv    = (const float*)d_in[6];
  const float* Wo    = (const float*)d_in[7];
  const float* bo    = (const float*)d_in[8];
  float* out = (float*)d_out;

  char* ws = (char*)d_ws;
  // workspace layout (bytes), total 61,374,720:
  //   wb4   bf16 4*768*768   @ 0           (4,718,592)
  //   pos   int  8192        @ 4,718,592   (32,768); nv int[2] @ +32,768
  //   Xqb   bf16 2048*768    @ 4,751,616   (3,145,728)   ml aliases (786,432)
  //   Xkc   bf16 8192*768    @ 7,897,344   (12,582,912)  Opart(bf16) aliases
  //   Xvc   bf16 8192*768    @ 20,480,256  (12,582,912)
  //   Qb    bf16 2048*768    @ 33,063,168  (3,145,728)   AObf aliases
  //   Kb    bf16 8192*768    @ 36,208,896  (12,582,912)
  //   VtG   bf16 24*64*4096  @ 48,791,808  (12,582,912)
  const size_t OFF_POS = 4718592,  OFF_XQ = 4751616,  OFF_XK = 7897344;
  const size_t OFF_XV  = 20480256, OFF_QB = 33063168, OFF_KB = 36208896;
  const size_t OFF_VT  = 48791808;
  __bf16* wb4  = (__bf16*)(ws);
  int*    pos  = (int*)(ws + OFF_POS);
  int*    nv   = (int*)(ws + OFF_POS + 32768);
  __bf16* Xqb  = (__bf16*)(ws + OFF_XQ);
  __bf16* Xkc  = (__bf16*)(ws + OFF_XK);
  __bf16* Xvc  = (__bf16*)(ws + OFF_XV);
  __bf16* Qb   = (__bf16*)(ws + OFF_QB);
  __bf16* AObf = Qb;                        // Qb dead after attn_fwd
  __bf16* Kb   = (__bf16*)(ws + OFF_KB);
  __bf16* VtG  = (__bf16*)(ws + OFF_VT);
  __bf16* Opb  = (__bf16*)(ws + OFF_XK);    // Xkc/Xvc dead after qkvproj
  float*  mlp  = (float*)(ws + OFF_XQ);     // Xqb dead after qkvproj

  const dim3 blk(256);
  prep0<<<dim3(2 + 1152 + 768), blk, 0, stream>>>(
      mask, pos, nv, Wq, Wk, Wv, Wo, wb4, query, Xqb);
  gatherkv<<<dim3(4096, 2), blk, 0, stream>>>(key, value, mask, pos, Xkc, Xvc);
  qkvproj<<<dim3(6, 144), blk, 0, stream>>>(Xqb, Xkc, Xvc, wb4, nv, Qb, Kb, VtG);

  attn_fwd<<<dim3(NQ / 64, NHEAD, BATCH * NSPLIT), blk, 0, stream>>>(
      Qb, Kb, VtG, nv, Opb, mlp);
  attn_combine<<<dim3((BH * NQ) / 4), blk, 0, stream>>>(Opb, mlp, AObf);

  outproj<<<dim3(6, 16), blk, 0, stream>>>(AObf, wb4 + 3 * 589824, out, bo);
}